// Round 4
// baseline (712.687 us; speedup 1.0000x reference)
//
#include <hip/hip_runtime.h>
#include <hip/hip_bf16.h>
#include <stdint.h>

#define S 2048
#define D 64
#define H 4096
#define NB 8

typedef __bf16 bf16;
typedef __attribute__((ext_vector_type(8))) __bf16 bf16x8;
typedef __attribute__((ext_vector_type(4))) __bf16 bf16x4;
typedef __attribute__((ext_vector_type(4))) float f32x4;
typedef __attribute__((ext_vector_type(16))) float f32x16;

// Raw LDS-DMA, invisible to the compiler's waitcnt pass (no auto vmcnt(0)).
// M0 = wave-uniform LDS byte offset; HW adds lane*16B. (R5-verified.)
__device__ __forceinline__ void dma16_raw(const bf16* g, uint32_t m0_bytes) {
  uint32_t m0s = __builtin_amdgcn_readfirstlane(m0_bytes);
  asm volatile("s_mov_b32 m0, %1\n\t"
               "global_load_lds_dwordx4 %0, off"
               :: "v"(g), "s"(m0s) : "memory");
}

__device__ __forceinline__ uint32_t lds_off_bytes(const void* p) {
  return (uint32_t)(uintptr_t)(__attribute__((address_space(3))) const void*)p;
}

// ---------------------------------------------------------------------------
// Transpose + cast: W [K][N] f32  ->  Wt [N][K] bf16   (weights, once per call)
// ---------------------------------------------------------------------------
__global__ __launch_bounds__(256) void transpose_cast(const float* __restrict__ W,
                                                      bf16* __restrict__ Wt,
                                                      int K, int N) {
  __shared__ float tile[64][65];
  int k0 = blockIdx.y * 64, n0 = blockIdx.x * 64;
  int c = threadIdx.x & 63;
  int r4 = threadIdx.x >> 6;
#pragma unroll
  for (int i = 0; i < 16; ++i) {
    int r = i * 4 + r4;
    tile[r][c] = W[(size_t)(k0 + r) * N + n0 + c];
  }
  __syncthreads();
#pragma unroll
  for (int i = 0; i < 16; ++i) {
    int r = i * 4 + r4;
    Wt[(size_t)(n0 + r) * K + k0 + c] = (bf16)tile[c][r];
  }
}

// ---------------------------------------------------------------------------
// Batched transpose + cast for V: V [z][S][D] f32 -> Vt [z][D][S] bf16.
// ---------------------------------------------------------------------------
__global__ __launch_bounds__(256) void vt_cast(const float* __restrict__ V,
                                               bf16* __restrict__ Vt) {
  __shared__ float tile[64][65];
  int z = blockIdx.y;
  int s0 = blockIdx.x * 64;
  const float* Vb = V + (size_t)z * (S * D);
  bf16* Vtb = Vt + (size_t)z * (D * S);
  int c = threadIdx.x & 63;
  int r4 = threadIdx.x >> 6;
#pragma unroll
  for (int i = 0; i < 16; ++i) {
    int r = i * 4 + r4;
    tile[r][c] = Vb[(size_t)(s0 + r) * D + c];
  }
  __syncthreads();
#pragma unroll
  for (int i = 0; i < 16; ++i) {
    int r = i * 4 + r4;  // r = d index
    Vtb[(size_t)r * S + s0 + c] = (bf16)tile[c][r];
  }
}

// ---------------------------------------------------------------------------
// Elementwise cast f32 -> bf16 (for Q, K). One float4 per thread.
// ---------------------------------------------------------------------------
__global__ __launch_bounds__(256) void cast_bf16(const float* __restrict__ x,
                                                 bf16* __restrict__ y) {
  int i = blockIdx.x * 256 + threadIdx.x;
  f32x4 v = ((const f32x4*)x)[i];
  bf16x4 o;
  o[0] = (bf16)v.x; o[1] = (bf16)v.y; o[2] = (bf16)v.z; o[3] = (bf16)v.w;
  ((bf16x4*)y)[i] = o;
}

// ---------------------------------------------------------------------------
// gemm_bt: kept (verified) for QK^T only (K=64 -> no deep pipeline to fill).
// ---------------------------------------------------------------------------
template <int RELU, int OUTBF16>
__global__ __launch_bounds__(256, 2) void gemm_bt(const bf16* __restrict__ A,
                                                  const bf16* __restrict__ Bt,
                                                  const float* __restrict__ bias,
                                                  void* __restrict__ Cv,
                                                  float scale,
                                                  int M, int N, int K,
                                                  long strideA, long strideB,
                                                  long strideC) {
  __shared__ __align__(16) bf16 smem[24576];
  int tid = threadIdx.x;
  int lane = tid & 63;
  int w = tid >> 6;

  int m0 = blockIdx.y * 128, n0 = blockIdx.x * 256;
  const bf16* Ab = A + (size_t)blockIdx.z * strideA;
  const bf16* Btb = Bt + (size_t)blockIdx.z * strideB;

  int grow = tid >> 2;
  int gcol = (((lane & 3) ^ ((lane >> 3) & 3)) * 8);
  const bf16* gA0 = Ab + (size_t)(m0 + grow) * K + gcol;
  const bf16* gA1 = gA0 + (size_t)64 * K;
  const bf16* gB0 = Btb + (size_t)(n0 + grow) * K + gcol;
  const bf16* gB1 = gB0 + (size_t)64 * K;
  const bf16* gB2 = gB0 + (size_t)128 * K;
  const bf16* gB3 = gB0 + (size_t)192 * K;

  uint32_t ldsBase = lds_off_bytes(&smem[0]);
  uint32_t wb = (uint32_t)(w * 1024);
  uint32_t mA[2], mB[2];
  mA[0] = ldsBase + wb;          mA[1] = ldsBase + 8192 + wb;
  mB[0] = ldsBase + 16384 + wb;  mB[1] = ldsBase + 32768 + wb;

  int mw = (w & 1) * 64, nw = (w >> 1) * 128;
  int lr = lane & 15;
  int ck = lane >> 4;
  int swz = (ck ^ ((lr >> 1) & 3)) * 8;
  const bf16* paBase = smem + (size_t)(mw + lr) * 32 + swz;
  const bf16* pbBase = smem + 8192 + (size_t)(nw + lr) * 32 + swz;

  f32x4 zero = {0.f, 0.f, 0.f, 0.f};
  f32x4 acc[4][8];
#pragma unroll
  for (int mt = 0; mt < 4; ++mt)
#pragma unroll
    for (int nt = 0; nt < 8; ++nt) acc[mt][nt] = zero;

  const int niter = K / 32;

#define STAGE(buf, koff)                                 \
  do {                                                   \
    dma16_raw(gA0 + (koff), mA[buf]);                    \
    dma16_raw(gA1 + (koff), mA[buf] + 4096);             \
    dma16_raw(gB0 + (koff), mB[buf]);                    \
    dma16_raw(gB1 + (koff), mB[buf] + 4096);             \
    dma16_raw(gB2 + (koff), mB[buf] + 8192);             \
    dma16_raw(gB3 + (koff), mB[buf] + 12288);            \
  } while (0)

  STAGE(0, 0);
  STAGE(1, 32);

  for (int it = 0; it < niter; ++it) {
    int buf = it & 1;
    asm volatile("s_waitcnt vmcnt(6)\n\ts_barrier" ::: "memory");
    const bf16* pa = paBase + buf * 4096;
    const bf16* pb = pbBase + buf * 8192;
    bf16x8 af[4], bfr[8];
#pragma unroll
    for (int mt = 0; mt < 4; ++mt) af[mt] = *(const bf16x8*)(pa + mt * (16 * 32));
#pragma unroll
    for (int nt = 0; nt < 8; ++nt) bfr[nt] = *(const bf16x8*)(pb + nt * (16 * 32));
    asm volatile("s_waitcnt lgkmcnt(0)\n\ts_barrier" ::: "memory");
    int kpre = it + 2 < niter ? (it + 2) * 32 : (niter - 1) * 32;
    STAGE(buf, kpre);
#pragma unroll
    for (int mt = 0; mt < 4; ++mt)
#pragma unroll
      for (int nt = 0; nt < 8; ++nt)
        acc[mt][nt] = __builtin_amdgcn_mfma_f32_16x16x32_bf16(af[mt], bfr[nt],
                                                              acc[mt][nt], 0, 0, 0);
  }
#undef STAGE
  asm volatile("s_waitcnt vmcnt(0)" ::: "memory");

  int mbase = m0 + mw + (lane >> 4) * 4;
  int nbase = n0 + nw + (lane & 15);
#pragma unroll
  for (int mt = 0; mt < 4; ++mt) {
#pragma unroll
    for (int nt = 0; nt < 8; ++nt) {
      int n = nbase + nt * 16;
      float bv = bias ? bias[n] : 0.f;
#pragma unroll
      for (int reg = 0; reg < 4; ++reg) {
        int m = mbase + mt * 16 + reg;
        float v = acc[mt][nt][reg] * scale + bv;
        if (RELU) v = fmaxf(v, 0.f);
        if (OUTBF16) {
          bf16* C = (bf16*)Cv + (size_t)blockIdx.z * strideC;
          C[(size_t)m * N + n] = (bf16)v;
        } else {
          float* C = (float*)Cv + (size_t)blockIdx.z * strideC;
          C[(size_t)m * N + n] = v;
        }
      }
    }
  }
}

// ---------------------------------------------------------------------------
// gemm256: 256x256 tile, BK=64, 512 threads (8 waves as 2Mx4N, 128x64/wave),
// 128 KiB LDS, counted-vmcnt quadrant schedule (R10: 4 barriers/tile,
// MFMA clusters head sections with next-phase reads/stages behind them).
// R11: inner shape 16x16x32 -> 32x32x16. Same FLOPs in half the MFMA
// instructions at 4096 FLOP/cyc (m119: 2495 TF ceiling) vs 3378 (m06).
// Per wave: 4x2 frags of 32x32 (acc = 8x f32x16 = 128 regs, unchanged).
// A/B frag: lane holds 8 contiguous k at row=lane&31, k0=(lane>>5)*8;
// LDS granule = (kg*2 + (lane>>5)) ^ (lane&7)  (same XOR involution as the
// staging pre-swizzle; per-8-row-stripe granules are a permutation of
// {0..7} -> conflict-free, same argument as the 16x16 layout which
// profiled 0 conflicts). Staging/DMA/vmcnt/barriers byte-identical to R10.
// ---------------------------------------------------------------------------
template <int RELU, int OUTBF16>
__global__ __launch_bounds__(512, 2) void gemm256(const bf16* __restrict__ A,
                                                  const bf16* __restrict__ Bt,
                                                  const float* __restrict__ bias,
                                                  void* __restrict__ Cv,
                                                  float scale,
                                                  int M, int N, int K,
                                                  long strideA, long strideB,
                                                  long strideC) {
  __shared__ __align__(16) bf16 smem[65536];  // 128 KiB
  const char* smc = (const char*)&smem[0];

  int tid = threadIdx.x;
  int lane = tid & 63;
  int w = tid >> 6;
  int wm = w >> 2, wn = w & 3;  // 2M x 4N wave grid

  // bijective XCD swizzle (m204) over the x-y plane; z = batch untouched.
  unsigned gx = gridDim.x;
  unsigned nwg = gx * gridDim.y;
  unsigned flat = blockIdx.y * gx + blockIdx.x;
  unsigned q = nwg >> 3, r = nwg & 7, xcd = flat & 7, idx = flat >> 3;
  unsigned wg = (xcd < r ? xcd * (q + 1) : r * (q + 1) + (xcd - r) * q) + idx;
  int n0 = (int)(wg % gx) * 256;
  int m0 = (int)(wg / gx) * 256;

  const bf16* Ab = A + (size_t)blockIdx.z * strideA;
  const bf16* Btb = Bt + (size_t)blockIdx.z * strideB;

  // Staging: thread t covers LDS byte 16*t of each 8 KiB (64-row) load chunk:
  // row = t>>3, granule = t&7. Pre-swizzled global granule = (t&7)^(row&7).
  int trow = tid >> 3;
  int tg = (tid & 7) ^ (trow & 7);
  const bf16* pgA = Ab + (size_t)(m0 + trow) * K + tg * 8;
  const bf16* pgB = Btb + (size_t)(n0 + trow) * K + tg * 8;
  const size_t s64K = (size_t)K * 64;

  uint32_t ldsBase = lds_off_bytes(&smem[0]);
  uint32_t mb = ldsBase + (uint32_t)(w * 1024);  // wave-uniform DMA base

  // LDS read bases (32x32x16 frags): row = lane&31, k0 = (lane>>5)*8.
  // byte = rowInHalf*128 + (((kg*2 + j) ^ (lane&7)) * 16), j = lane>>5.
  int j = lane >> 5, r3 = lane & 7;
  uint32_t gOff[4];
#pragma unroll
  for (int kg = 0; kg < 4; ++kg)
    gOff[kg] = (uint32_t)((((kg * 2 + j) ^ r3) * 16));
  uint32_t rbA = (uint32_t)(wm * 8192 + (lane & 31) * 128);
  uint32_t rbB = (uint32_t)(65536 + wn * 4096 + (lane & 31) * 128);

  f32x16 acc[4][2];  // [qa*2+rg][qb]
#pragma unroll
  for (int a = 0; a < 4; ++a)
#pragma unroll
    for (int b = 0; b < 2; ++b)
#pragma unroll
      for (int e = 0; e < 16; ++e) acc[a][b][e] = 0.f;

  bf16x8 af[2][4];  // current A quad [rg][kg]
  bf16x8 bf0[4];    // B quad 0 (held ph0 -> ph3, no re-read)
  bf16x8 bf1[4];    // B quad 1

#define STG_A(PI, HH, LL, KC) \
  dma16_raw(pgA + (size_t)(2 * (HH) + (LL)) * s64K + (KC), \
            mb + (PI) * 32768 + (HH) * 16384 + (LL) * 8192)
#define STG_B(PI, HH, LL, KC) \
  dma16_raw(pgB + (size_t)(2 * (HH) + (LL)) * s64K + (KC), \
            mb + 65536 + (PI) * 32768 + (HH) * 16384 + (LL) * 8192)
#define STAGE_AH(PI, HH, KC) do { STG_A(PI, HH, 0, KC); STG_A(PI, HH, 1, KC); } while (0)
#define STAGE_BH(PI, HH, KC) do { STG_B(PI, HH, 0, KC); STG_B(PI, HH, 1, KC); } while (0)

#define RDA(PI, QA)                                                            \
  do {                                                                         \
    _Pragma("unroll") for (int rg = 0; rg < 2; ++rg)                           \
      _Pragma("unroll") for (int kg = 0; kg < 4; ++kg)                         \
        af[rg][kg] = *(const bf16x8*)(smc + rbA + rg * 4096 + gOff[kg] +       \
                                      ((PI) * 32768 + (QA) * 16384));          \
  } while (0)
#define RDB(PI, QB, BF)                                                        \
  do {                                                                         \
    _Pragma("unroll") for (int kg = 0; kg < 4; ++kg)                           \
      BF[kg] = *(const bf16x8*)(smc + rbB + gOff[kg] +                         \
                                ((PI) * 32768 + (QB) * 16384));                \
  } while (0)

#define MFMA_Q(QA, QB, BF)                                                     \
  do {                                                                         \
    __builtin_amdgcn_s_setprio(1);                                             \
    _Pragma("unroll") for (int kg = 0; kg < 4; ++kg)                           \
      _Pragma("unroll") for (int rg = 0; rg < 2; ++rg)                         \
        acc[(QA) * 2 + rg][QB] = __builtin_amdgcn_mfma_f32_32x32x16_bf16(      \
            af[rg][kg], BF[kg], acc[(QA) * 2 + rg][QB], 0, 0, 0);              \
    __builtin_amdgcn_s_setprio(0);                                             \
  } while (0)

#define BAR() asm volatile("s_barrier" ::: "memory")
#define VMC4() asm volatile("s_waitcnt vmcnt(4)" ::: "memory")

  // One K-tile, 4 barriers. MFMA clusters head sections; next-phase reads
  // and stages issue behind them (LDS drains under the MFMA window).
#define TILE(PI, KC1, KC2)            \
  do {                                \
    RDA(PI, 0);                       \
    RDB(PI, 0, bf0);                  \
    STAGE_AH((PI) ^ 1, 1, KC1);       \
    BAR();                            \
    MFMA_Q(0, 0, bf0);                \
    RDB(PI, 1, bf1);                  \
    STAGE_BH((PI) ^ 1, 0, KC1);       \
    BAR();                            \
    MFMA_Q(0, 1, bf1);                \
    RDA(PI, 1);                       \
    STAGE_AH(PI, 0, KC2);             \
    BAR();                            \
    MFMA_Q(1, 1, bf1);                \
    STAGE_BH(PI, 1, KC2);             \
    MFMA_Q(1, 0, bf0);                \
    VMC4();                           \
    BAR();                            \
  } while (0)

  // Prologue: issue halves in steady-state order so vmcnt(4) leaves exactly
  // the two tile-1 (ph2/ph3-slot) halves outstanding.
  STAGE_AH(0, 0, 0);
  STAGE_BH(0, 1, 0);
  STAGE_AH(0, 1, 0);
  STAGE_BH(0, 0, 0);
  STAGE_AH(1, 0, 64);
  STAGE_BH(1, 1, 64);
  asm volatile("s_waitcnt vmcnt(4)\n\ts_barrier" ::: "memory");

  const int NT = K / 64;  // even (K = 2048 or 4096)
  for (int T = 0; T < NT; T += 2) {
    int c1 = (T + 1) * 64;
    int c2 = (T + 2 < NT ? T + 2 : NT - 1) * 64;  // tail: clamp DATA only;
    int c3 = (T + 3 < NT ? T + 3 : NT - 1) * 64;  // dest slots are never read
    TILE(0, c1, c2);
    TILE(1, c2, c3);
  }
#undef TILE
#undef VMC4
#undef BAR
#undef MFMA_Q
#undef RDB
#undef RDA
#undef STAGE_BH
#undef STAGE_AH
#undef STG_B
#undef STG_A

  asm volatile("s_waitcnt vmcnt(0)" ::: "memory");

  // epilogue; 32x32 C/D layout: col = lane&31, row = (reg&3)+8*(reg>>2)+4*(lane>>5)
  int rowb0 = m0 + wm * 64 + 4 * (lane >> 5);
  int colb0 = n0 + wn * 32 + (lane & 31);
#pragma unroll
  for (int qb = 0; qb < 2; ++qb) {
    int n = colb0 + qb * 128;
    float bv = bias ? bias[n] : 0.f;
#pragma unroll
    for (int fm = 0; fm < 4; ++fm) {
      int rowb = rowb0 + (fm >> 1) * 128 + (fm & 1) * 32;
#pragma unroll
      for (int reg = 0; reg < 16; ++reg) {
        int m = rowb + (reg & 3) + 8 * (reg >> 2);
        float v = acc[fm][qb][reg] * scale + bv;
        if (RELU) v = fmaxf(v, 0.f);
        if (OUTBF16) {
          bf16* C = (bf16*)Cv + (size_t)blockIdx.z * strideC;
          C[(size_t)m * N + n] = (bf16)v;
        } else {
          float* C = (float*)Cv + (size_t)blockIdx.z * strideC;
          C[(size_t)m * N + n] = v;
        }
      }
    }
  }
}

// ---------------------------------------------------------------------------
// smav: fused softmax + attn@V on MFMA (R9; replaced 128us scalar AV).
// ---------------------------------------------------------------------------
__global__ __launch_bounds__(256) void smav(const float* __restrict__ adj,
                                            const bf16* __restrict__ Vt,
                                            float* __restrict__ out,
                                            long adjStride) {
  int z = blockIdx.y;
  const float* adjb = adj + (size_t)z * adjStride;
  const bf16* Vtb = Vt + (size_t)z * (D * S);
  float* outb = out + (size_t)z * (S * D);
  int q0 = blockIdx.x * 16;
  __shared__ __align__(16) bf16 P[16 * 2048];  // 64 KiB, swizzled
  __shared__ float rsum[16];
  int tid = threadIdx.x, w = tid >> 6, lane = tid & 63;
  char* Pc = (char*)&P[0];

  // ---- phase 1: softmax (rows w*4 .. w*4+3) ----
#pragma unroll
  for (int i = 0; i < 4; ++i) {
    int r = w * 4 + i;
    const float* rowp = adjb + (size_t)(q0 + r) * S + lane * 4;
    f32x4 rv[8];
    float lm = -1e30f;
#pragma unroll
    for (int kk = 0; kk < 8; ++kk) {
      rv[kk] = *(const f32x4*)(rowp + kk * 256);
      lm = fmaxf(lm, fmaxf(fmaxf(rv[kk].x, rv[kk].y), fmaxf(rv[kk].z, rv[kk].w)));
    }
#pragma unroll
    for (int off = 32; off > 0; off >>= 1) lm = fmaxf(lm, __shfl_xor(lm, off));
    float s = 0.f;
    uint32_t wbase = (uint32_t)(r * 4096 + (lane & 1) * 8);
#pragma unroll
    for (int kk = 0; kk < 8; ++kk) {
      bf16x4 pb;
      pb[0] = (bf16)__expf(rv[kk].x - lm);
      pb[1] = (bf16)__expf(rv[kk].y - lm);
      pb[2] = (bf16)__expf(rv[kk].z - lm);
      pb[3] = (bf16)__expf(rv[kk].w - lm);
      s += (float)pb[0] + (float)pb[1] + (float)pb[2] + (float)pb[3];
      uint32_t g = (uint32_t)(lane >> 1) + (uint32_t)(kk * 32);
      uint32_t gs = g ^ (uint32_t)(r & 7);  // low-3-bit XOR (granule swizzle)
      *(bf16x4*)(Pc + wbase + gs * 16) = pb;
    }
#pragma unroll
    for (int off = 32; off > 0; off >>= 1) s += __shfl_xor(s, off);
    if (lane == 0) rsum[r] = s;
  }
  __syncthreads();

  // ---- phase 2: out[q0..q0+16)[d0..d0+16) = P @ V^T-frag, MFMA ----
  int dl = (w << 4) + (lane & 15);
  const bf16* vrow = Vtb + (size_t)dl * S + (lane >> 4) * 8;
  uint32_t rl = (uint32_t)(lane & 15);
  uint32_t abase = rl * 4096;
  uint32_t rx = rl & 7;
  f32x4 acc0 = {0.f, 0.f, 0.f, 0.f}, acc1 = {0.f, 0.f, 0.f, 0.f};
#pragma unroll 4
  for (int k0 = 0; k0 < S; k0 += 64) {
    uint32_t g0 = (uint32_t)(k0 >> 3) + (uint32_t)(lane >> 4);
    bf16x8 a0 = *(const bf16x8*)(Pc + abase + ((g0 ^ rx) * 16));
    bf16x8 b0 = *(const bf16x8*)(vrow + k0);
    acc0 = __builtin_amdgcn_mfma_f32_16x16x32_bf16(a0, b0, acc0, 0, 0, 0);
    uint32_t g1 = g0 + 4;
    bf16x8 a1 = *(const bf16x8*)(Pc + abase + ((g1 ^ rx) * 16));
    bf16x8 b1 = *(const bf16x8*)(vrow + k0 + 32);
    acc1 = __builtin_amdgcn_mfma_f32_16x16x32_bf16(a1, b1, acc1, 0, 0, 0);
  }
  f32x4 accs = acc0 + acc1;
#pragma unroll
  for (int reg = 0; reg < 4; ++reg) {
    int m = ((lane >> 4) << 2) + reg;  // C/D layout: row=(lane>>4)*4+reg
    outb[(size_t)(q0 + m) * D + dl] = accs[reg] / rsum[m];
  }
}

// ---------------------------------------------------------------------------
extern "C" void kernel_launch(void* const* d_in, const int* in_sizes, int n_in,
                              void* d_out, int out_size, void* d_ws, size_t ws_size,
                              hipStream_t stream) {
  const float* Q  = (const float*)d_in[0];
  const float* Km = (const float*)d_in[1];
  const float* V  = (const float*)d_in[2];
  const float* W1 = (const float*)d_in[3];
  const float* b1 = (const float*)d_in[4];
  const float* W2 = (const float*)d_in[5];
  const float* b2 = (const float*)d_in[6];
  float* out = (float*)d_out;
  char* ws = (char*)d_ws;

  // layout: W1t 16M | W2t 16M | Qb16 2M | Kb16 2M | X (Sc bf16 / adj f32,
  // aliased) G*16M | h G*16M.  footprint = 36M + G*32M bytes.
  // Vt (bf16 [G][D][S], G*256KB) aliases the h region: written AFTER the
  // W2 gemm consumed h each group iteration, consumed by smav.
  bf16* W1t  = (bf16*)ws;
  bf16* W2t  = (bf16*)(ws + 16777216);
  bf16* Qb16 = (bf16*)(ws + 33554432);
  bf16* Kb16 = (bf16*)(ws + 35651584);

  transpose_cast<<<dim3(H / 64, S / 64), 256, 0, stream>>>(W1, W1t, S, H);
  transpose_cast<<<dim3(S / 64, H / 64), 256, 0, stream>>>(W2, W2t, H, S);
  cast_bf16<<<dim3(NB * S * D / 1024), 256, 0, stream>>>(Q, Qb16);
  cast_bf16<<<dim3(NB * S * D / 1024), 256, 0, stream>>>(Km, Kb16);

  int G = 1;
  if (ws_size >= 306184192ULL) G = 8;        // 292 MiB (R7 ran G=8 OK)
  else if (ws_size >= 171966464ULL) G = 4;
  else if (ws_size >= 104857600ULL) G = 2;

  bf16* Sc   = (bf16*)(ws + 37748736);
  float* adj = (float*)(ws + 37748736);
  bf16* h    = (bf16*)(ws + 37748736 + (size_t)G * 16777216);
  bf16* Vt   = h;  // alias, see layout note

  for (int b0 = 0; b0 < NB; b0 += G) {
    // scores = (Q @ K^T) / 8 via MFMA (K-dim = 64: keep the verified gemm_bt)
    gemm_bt<0, 1><<<dim3(S / 256, S / 128, G), 256, 0, stream>>>(
        Qb16 + (size_t)b0 * S * D, Kb16 + (size_t)b0 * S * D, nullptr, Sc,
        0.125f, S, S, D, (long)S * D, (long)S * D, (long)S * S);
    // big MLP GEMMs on the 4-barrier overlap schedule, 32x32x16 MFMA
    gemm256<1, 1><<<dim3(H / 256, S / 256, G), 512, 0, stream>>>(
        Sc, W1t, b1, h, 1.0f, S, H, S, (long)S * S, 0L, (long)S * H);
    gemm256<0, 0><<<dim3(S / 256, S / 256, G), 512, 0, stream>>>(
        h, W2t, b2, adj, 1.0f, S, S, H, (long)S * H, 0L, (long)S * S);
    // V^T bf16 into the now-dead h region, then fused softmax + AV on MFMA
    vt_cast<<<dim3(S / 64, G), 256, 0, stream>>>(V + (size_t)b0 * S * D, Vt);
    smav<<<dim3(S / 16, G), 256, 0, stream>>>(
        adj, Vt, out + (size_t)b0 * S * D, (long)S * S);
  }
}

// Round 5
// 659.732 us; speedup vs baseline: 1.0803x; 1.0803x over previous
//
#include <hip/hip_runtime.h>
#include <hip/hip_bf16.h>
#include <stdint.h>

#define S 2048
#define D 64
#define H 4096
#define NB 8

typedef __bf16 bf16;
typedef __attribute__((ext_vector_type(8))) __bf16 bf16x8;
typedef __attribute__((ext_vector_type(4))) __bf16 bf16x4;
typedef __attribute__((ext_vector_type(4))) float f32x4;

// Raw LDS-DMA, invisible to the compiler's waitcnt pass (no auto vmcnt(0)).
// M0 = wave-uniform LDS byte offset; HW adds lane*16B. (R5-verified.)
__device__ __forceinline__ void dma16_raw(const bf16* g, uint32_t m0_bytes) {
  uint32_t m0s = __builtin_amdgcn_readfirstlane(m0_bytes);
  asm volatile("s_mov_b32 m0, %1\n\t"
               "global_load_lds_dwordx4 %0, off"
               :: "v"(g), "s"(m0s) : "memory");
}

__device__ __forceinline__ uint32_t lds_off_bytes(const void* p) {
  return (uint32_t)(uintptr_t)(__attribute__((address_space(3))) const void*)p;
}

// ---------------------------------------------------------------------------
// Transpose + cast: W [K][N] f32  ->  Wt [N][K] bf16   (weights, once per call)
// ---------------------------------------------------------------------------
__global__ __launch_bounds__(256) void transpose_cast(const float* __restrict__ W,
                                                      bf16* __restrict__ Wt,
                                                      int K, int N) {
  __shared__ float tile[64][65];
  int k0 = blockIdx.y * 64, n0 = blockIdx.x * 64;
  int c = threadIdx.x & 63;
  int r4 = threadIdx.x >> 6;
#pragma unroll
  for (int i = 0; i < 16; ++i) {
    int r = i * 4 + r4;
    tile[r][c] = W[(size_t)(k0 + r) * N + n0 + c];
  }
  __syncthreads();
#pragma unroll
  for (int i = 0; i < 16; ++i) {
    int r = i * 4 + r4;
    Wt[(size_t)(n0 + r) * K + k0 + c] = (bf16)tile[c][r];
  }
}

// ---------------------------------------------------------------------------
// Batched transpose + cast for V: V [z][S][D] f32 -> Vt [z][D][S] bf16.
// ---------------------------------------------------------------------------
__global__ __launch_bounds__(256) void vt_cast(const float* __restrict__ V,
                                               bf16* __restrict__ Vt) {
  __shared__ float tile[64][65];
  int z = blockIdx.y;
  int s0 = blockIdx.x * 64;
  const float* Vb = V + (size_t)z * (S * D);
  bf16* Vtb = Vt + (size_t)z * (D * S);
  int c = threadIdx.x & 63;
  int r4 = threadIdx.x >> 6;
#pragma unroll
  for (int i = 0; i < 16; ++i) {
    int r = i * 4 + r4;
    tile[r][c] = Vb[(size_t)(s0 + r) * D + c];
  }
  __syncthreads();
#pragma unroll
  for (int i = 0; i < 16; ++i) {
    int r = i * 4 + r4;  // r = d index
    Vtb[(size_t)r * S + s0 + c] = (bf16)tile[c][r];
  }
}

// ---------------------------------------------------------------------------
// Elementwise cast f32 -> bf16 (for Q, K). One float4 per thread.
// ---------------------------------------------------------------------------
__global__ __launch_bounds__(256) void cast_bf16(const float* __restrict__ x,
                                                 bf16* __restrict__ y) {
  int i = blockIdx.x * 256 + threadIdx.x;
  f32x4 v = ((const f32x4*)x)[i];
  bf16x4 o;
  o[0] = (bf16)v.x; o[1] = (bf16)v.y; o[2] = (bf16)v.z; o[3] = (bf16)v.w;
  ((bf16x4*)y)[i] = o;
}

// ---------------------------------------------------------------------------
// gemm_bt: kept (verified) for QK^T only (K=64 -> no deep pipeline to fill).
// ---------------------------------------------------------------------------
template <int RELU, int OUTBF16>
__global__ __launch_bounds__(256, 2) void gemm_bt(const bf16* __restrict__ A,
                                                  const bf16* __restrict__ Bt,
                                                  const float* __restrict__ bias,
                                                  void* __restrict__ Cv,
                                                  float scale,
                                                  int M, int N, int K,
                                                  long strideA, long strideB,
                                                  long strideC) {
  __shared__ __align__(16) bf16 smem[24576];
  int tid = threadIdx.x;
  int lane = tid & 63;
  int w = tid >> 6;

  int m0 = blockIdx.y * 128, n0 = blockIdx.x * 256;
  const bf16* Ab = A + (size_t)blockIdx.z * strideA;
  const bf16* Btb = Bt + (size_t)blockIdx.z * strideB;

  int grow = tid >> 2;
  int gcol = (((lane & 3) ^ ((lane >> 3) & 3)) * 8);
  const bf16* gA0 = Ab + (size_t)(m0 + grow) * K + gcol;
  const bf16* gA1 = gA0 + (size_t)64 * K;
  const bf16* gB0 = Btb + (size_t)(n0 + grow) * K + gcol;
  const bf16* gB1 = gB0 + (size_t)64 * K;
  const bf16* gB2 = gB0 + (size_t)128 * K;
  const bf16* gB3 = gB0 + (size_t)192 * K;

  uint32_t ldsBase = lds_off_bytes(&smem[0]);
  uint32_t wb = (uint32_t)(w * 1024);
  uint32_t mA[2], mB[2];
  mA[0] = ldsBase + wb;          mA[1] = ldsBase + 8192 + wb;
  mB[0] = ldsBase + 16384 + wb;  mB[1] = ldsBase + 32768 + wb;

  int mw = (w & 1) * 64, nw = (w >> 1) * 128;
  int lr = lane & 15;
  int ck = lane >> 4;
  int swz = (ck ^ ((lr >> 1) & 3)) * 8;
  const bf16* paBase = smem + (size_t)(mw + lr) * 32 + swz;
  const bf16* pbBase = smem + 8192 + (size_t)(nw + lr) * 32 + swz;

  f32x4 zero = {0.f, 0.f, 0.f, 0.f};
  f32x4 acc[4][8];
#pragma unroll
  for (int mt = 0; mt < 4; ++mt)
#pragma unroll
    for (int nt = 0; nt < 8; ++nt) acc[mt][nt] = zero;

  const int niter = K / 32;

#define STAGE(buf, koff)                                 \
  do {                                                   \
    dma16_raw(gA0 + (koff), mA[buf]);                    \
    dma16_raw(gA1 + (koff), mA[buf] + 4096);             \
    dma16_raw(gB0 + (koff), mB[buf]);                    \
    dma16_raw(gB1 + (koff), mB[buf] + 4096);             \
    dma16_raw(gB2 + (koff), mB[buf] + 8192);             \
    dma16_raw(gB3 + (koff), mB[buf] + 12288);            \
  } while (0)

  STAGE(0, 0);
  STAGE(1, 32);

  for (int it = 0; it < niter; ++it) {
    int buf = it & 1;
    asm volatile("s_waitcnt vmcnt(6)\n\ts_barrier" ::: "memory");
    const bf16* pa = paBase + buf * 4096;
    const bf16* pb = pbBase + buf * 8192;
    bf16x8 af[4], bfr[8];
#pragma unroll
    for (int mt = 0; mt < 4; ++mt) af[mt] = *(const bf16x8*)(pa + mt * (16 * 32));
#pragma unroll
    for (int nt = 0; nt < 8; ++nt) bfr[nt] = *(const bf16x8*)(pb + nt * (16 * 32));
    asm volatile("s_waitcnt lgkmcnt(0)\n\ts_barrier" ::: "memory");
    int kpre = it + 2 < niter ? (it + 2) * 32 : (niter - 1) * 32;
    STAGE(buf, kpre);
#pragma unroll
    for (int mt = 0; mt < 4; ++mt)
#pragma unroll
      for (int nt = 0; nt < 8; ++nt)
        acc[mt][nt] = __builtin_amdgcn_mfma_f32_16x16x32_bf16(af[mt], bfr[nt],
                                                              acc[mt][nt], 0, 0, 0);
  }
#undef STAGE
  asm volatile("s_waitcnt vmcnt(0)" ::: "memory");

  int mbase = m0 + mw + (lane >> 4) * 4;
  int nbase = n0 + nw + (lane & 15);
#pragma unroll
  for (int mt = 0; mt < 4; ++mt) {
#pragma unroll
    for (int nt = 0; nt < 8; ++nt) {
      int n = nbase + nt * 16;
      float bv = bias ? bias[n] : 0.f;
#pragma unroll
      for (int reg = 0; reg < 4; ++reg) {
        int m = mbase + mt * 16 + reg;
        float v = acc[mt][nt][reg] * scale + bv;
        if (RELU) v = fmaxf(v, 0.f);
        if (OUTBF16) {
          bf16* C = (bf16*)Cv + (size_t)blockIdx.z * strideC;
          C[(size_t)m * N + n] = (bf16)v;
        } else {
          float* C = (float*)Cv + (size_t)blockIdx.z * strideC;
          C[(size_t)m * N + n] = v;
        }
      }
    }
  }
}

// ---------------------------------------------------------------------------
// gemm256: 256x256 tile, BK=64, 512 threads (8 waves as 2Mx4N, 128x64/wave),
// 128 KiB LDS, counted-vmcnt quadrant schedule (R10: 4 barriers/tile,
// MFMA clusters head sections with next-phase reads/stages behind them).
// R12: REVERT of R11's 32x32x16 experiment — it introduced 1.26e7 LDS bank
// conflicts/dispatch (118 -> 137 us). The 16x16x32 read layout below is the
// PMC-verified conflict-free one (0 conflicts across R8-R10). Do not change
// the fragment read pattern without re-measuring SQ_LDS_BANK_CONFLICT.
// Safety invariants (R8-derived, unchanged):
//  - every region's ds_reads are consumed (lgkmcnt-drained) before that
//    wave's next barrier; every overwriting STAGE sits >=1 barrier later.
//  - DMA issue order per tile (AH[PI^1,h1], BH[PI^1,h0], AH[PI,h0],
//    BH[PI,h1]) + once-per-tile vmcnt(4): at each tile boundary exactly
//    the two tile+2 halves may be outstanding.
// ---------------------------------------------------------------------------
template <int RELU, int OUTBF16>
__global__ __launch_bounds__(512, 2) void gemm256(const bf16* __restrict__ A,
                                                  const bf16* __restrict__ Bt,
                                                  const float* __restrict__ bias,
                                                  void* __restrict__ Cv,
                                                  float scale,
                                                  int M, int N, int K,
                                                  long strideA, long strideB,
                                                  long strideC) {
  __shared__ __align__(16) bf16 smem[65536];  // 128 KiB
  const char* smc = (const char*)&smem[0];

  int tid = threadIdx.x;
  int lane = tid & 63;
  int w = tid >> 6;
  int wm = w >> 2, wn = w & 3;  // 2M x 4N wave grid

  // bijective XCD swizzle (m204) over the x-y plane; z = batch untouched.
  unsigned gx = gridDim.x;
  unsigned nwg = gx * gridDim.y;
  unsigned flat = blockIdx.y * gx + blockIdx.x;
  unsigned q = nwg >> 3, r = nwg & 7, xcd = flat & 7, idx = flat >> 3;
  unsigned wg = (xcd < r ? xcd * (q + 1) : r * (q + 1) + (xcd - r) * q) + idx;
  int n0 = (int)(wg % gx) * 256;
  int m0 = (int)(wg / gx) * 256;

  const bf16* Ab = A + (size_t)blockIdx.z * strideA;
  const bf16* Btb = Bt + (size_t)blockIdx.z * strideB;

  // Staging: thread t covers LDS byte 16*t of each 8 KiB (64-row) load chunk:
  // row = t>>3, granule = t&7. Pre-swizzled global granule = (t&7)^(row&7).
  int trow = tid >> 3;
  int tg = (tid & 7) ^ (trow & 7);
  const bf16* pgA = Ab + (size_t)(m0 + trow) * K + tg * 8;
  const bf16* pgB = Btb + (size_t)(n0 + trow) * K + tg * 8;
  const size_t s64K = (size_t)K * 64;

  uint32_t ldsBase = lds_off_bytes(&smem[0]);
  uint32_t mb = ldsBase + (uint32_t)(w * 1024);  // wave-uniform DMA base

  // LDS read bases. A-frag (16x16x32): row=lane&15, k=(lane>>4)*8.
  int j = lane >> 4, b2 = (lane >> 2) & 1;
  uint32_t rbA0 = (uint32_t)(wm * 8192 + (lane & 15) * 128 +
                             ((j ^ (lane & 3)) * 16) + b2 * 64);
  uint32_t rbA1 = rbA0 ^ 64u;
  uint32_t rbB0 = (uint32_t)(65536 + wn * 4096 + (lane & 15) * 128 +
                             ((j ^ (lane & 3)) * 16) + b2 * 64);
  uint32_t rbB1 = rbB0 ^ 64u;

  f32x4 acc[8][4];  // [qa*4+mt][qb*2+nt]
#pragma unroll
  for (int a = 0; a < 8; ++a)
#pragma unroll
    for (int b = 0; b < 2 * 2; ++b) acc[a][b] = (f32x4){0.f, 0.f, 0.f, 0.f};

  bf16x8 af[4][2];   // current A quad [mt][kk]
  bf16x8 bf0[2][2];  // B quad 0 (held ph0 -> ph3, no re-read)
  bf16x8 bf1[2][2];  // B quad 1

#define STG_A(PI, HH, LL, KC) \
  dma16_raw(pgA + (size_t)(2 * (HH) + (LL)) * s64K + (KC), \
            mb + (PI) * 32768 + (HH) * 16384 + (LL) * 8192)
#define STG_B(PI, HH, LL, KC) \
  dma16_raw(pgB + (size_t)(2 * (HH) + (LL)) * s64K + (KC), \
            mb + 65536 + (PI) * 32768 + (HH) * 16384 + (LL) * 8192)
#define STAGE_AH(PI, HH, KC) do { STG_A(PI, HH, 0, KC); STG_A(PI, HH, 1, KC); } while (0)
#define STAGE_BH(PI, HH, KC) do { STG_B(PI, HH, 0, KC); STG_B(PI, HH, 1, KC); } while (0)

#define RDA(PI, QA)                                                            \
  do {                                                                        \
    _Pragma("unroll") for (int mt = 0; mt < 4; ++mt) {                        \
      af[mt][0] = *(const bf16x8*)(smc + rbA0 + ((PI) * 32768 + (QA) * 16384 + mt * 2048)); \
      af[mt][1] = *(const bf16x8*)(smc + rbA1 + ((PI) * 32768 + (QA) * 16384 + mt * 2048)); \
    }                                                                         \
  } while (0)
#define RDB(PI, QB, BF)                                                        \
  do {                                                                        \
    _Pragma("unroll") for (int nt = 0; nt < 2; ++nt) {                        \
      BF[nt][0] = *(const bf16x8*)(smc + rbB0 + ((PI) * 32768 + (QB) * 16384 + nt * 2048)); \
      BF[nt][1] = *(const bf16x8*)(smc + rbB1 + ((PI) * 32768 + (QB) * 16384 + nt * 2048)); \
    }                                                                         \
  } while (0)

#define MFMA_Q(QA, QB, BF)                                                     \
  do {                                                                        \
    __builtin_amdgcn_s_setprio(1);                                            \
    _Pragma("unroll") for (int mt = 0; mt < 4; ++mt)                          \
      _Pragma("unroll") for (int nt = 0; nt < 2; ++nt) {                      \
        f32x4 c = acc[(QA) * 4 + mt][(QB) * 2 + nt];                          \
        c = __builtin_amdgcn_mfma_f32_16x16x32_bf16(af[mt][0], BF[nt][0], c, 0, 0, 0); \
        c = __builtin_amdgcn_mfma_f32_16x16x32_bf16(af[mt][1], BF[nt][1], c, 0, 0, 0); \
        acc[(QA) * 4 + mt][(QB) * 2 + nt] = c;                                \
      }                                                                       \
    __builtin_amdgcn_s_setprio(0);                                            \
  } while (0)

#define BAR() asm volatile("s_barrier" ::: "memory")
#define VMC4() asm volatile("s_waitcnt vmcnt(4)" ::: "memory")

  // One K-tile, 4 barriers. MFMA clusters head sections; next-phase reads
  // and stages issue behind them (LDS drains under the MFMA window).
#define TILE(PI, KC1, KC2)            \
  do {                                \
    RDA(PI, 0);                       \
    RDB(PI, 0, bf0);                  \
    STAGE_AH((PI) ^ 1, 1, KC1);       \
    BAR();                            \
    MFMA_Q(0, 0, bf0);                \
    RDB(PI, 1, bf1);                  \
    STAGE_BH((PI) ^ 1, 0, KC1);       \
    BAR();                            \
    MFMA_Q(0, 1, bf1);                \
    RDA(PI, 1);                       \
    STAGE_AH(PI, 0, KC2);             \
    BAR();                            \
    MFMA_Q(1, 1, bf1);                \
    STAGE_BH(PI, 1, KC2);             \
    MFMA_Q(1, 0, bf0);                \
    VMC4();                           \
    BAR();                            \
  } while (0)

  // Prologue: issue halves in steady-state order so vmcnt(4) leaves exactly
  // the two tile-1 (ph2/ph3-slot) halves outstanding.
  STAGE_AH(0, 0, 0);
  STAGE_BH(0, 1, 0);
  STAGE_AH(0, 1, 0);
  STAGE_BH(0, 0, 0);
  STAGE_AH(1, 0, 64);
  STAGE_BH(1, 1, 64);
  asm volatile("s_waitcnt vmcnt(4)\n\ts_barrier" ::: "memory");

  const int NT = K / 64;  // even (K = 2048 or 4096)
  for (int T = 0; T < NT; T += 2) {
    int c1 = (T + 1) * 64;
    int c2 = (T + 2 < NT ? T + 2 : NT - 1) * 64;  // tail: clamp DATA only;
    int c3 = (T + 3 < NT ? T + 3 : NT - 1) * 64;  // dest slots are never read
    TILE(0, c1, c2);
    TILE(1, c2, c3);
  }
#undef TILE
#undef VMC4
#undef BAR
#undef MFMA_Q
#undef RDB
#undef RDA
#undef STAGE_BH
#undef STAGE_AH
#undef STG_B
#undef STG_A

  asm volatile("s_waitcnt vmcnt(0)" ::: "memory");

  int rowb = m0 + wm * 64 + ((lane >> 4) << 2);
  int colb = n0 + wn * 32 + (lane & 15);
#pragma unroll
  for (int fn = 0; fn < 4; ++fn) {
    int n = colb + (fn >> 1) * 128 + (fn & 1) * 16;
    float bv = bias ? bias[n] : 0.f;
#pragma unroll
    for (int fm = 0; fm < 8; ++fm) {
      int mrow = rowb + (fm >> 2) * 128 + (fm & 3) * 16;
#pragma unroll
      for (int reg = 0; reg < 4; ++reg) {
        float v = acc[fm][fn][reg] * scale + bv;
        if (RELU) v = fmaxf(v, 0.f);
        int m = mrow + reg;
        if (OUTBF16) {
          bf16* C = (bf16*)Cv + (size_t)blockIdx.z * strideC;
          C[(size_t)m * N + n] = (bf16)v;
        } else {
          float* C = (float*)Cv + (size_t)blockIdx.z * strideC;
          C[(size_t)m * N + n] = v;
        }
      }
    }
  }
}

// ---------------------------------------------------------------------------
// smav: fused softmax + attn@V on MFMA (R9; replaced 128us scalar AV).
// ---------------------------------------------------------------------------
__global__ __launch_bounds__(256) void smav(const float* __restrict__ adj,
                                            const bf16* __restrict__ Vt,
                                            float* __restrict__ out,
                                            long adjStride) {
  int z = blockIdx.y;
  const float* adjb = adj + (size_t)z * adjStride;
  const bf16* Vtb = Vt + (size_t)z * (D * S);
  float* outb = out + (size_t)z * (S * D);
  int q0 = blockIdx.x * 16;
  __shared__ __align__(16) bf16 P[16 * 2048];  // 64 KiB, swizzled
  __shared__ float rsum[16];
  int tid = threadIdx.x, w = tid >> 6, lane = tid & 63;
  char* Pc = (char*)&P[0];

  // ---- phase 1: softmax (rows w*4 .. w*4+3) ----
#pragma unroll
  for (int i = 0; i < 4; ++i) {
    int r = w * 4 + i;
    const float* rowp = adjb + (size_t)(q0 + r) * S + lane * 4;
    f32x4 rv[8];
    float lm = -1e30f;
#pragma unroll
    for (int kk = 0; kk < 8; ++kk) {
      rv[kk] = *(const f32x4*)(rowp + kk * 256);
      lm = fmaxf(lm, fmaxf(fmaxf(rv[kk].x, rv[kk].y), fmaxf(rv[kk].z, rv[kk].w)));
    }
#pragma unroll
    for (int off = 32; off > 0; off >>= 1) lm = fmaxf(lm, __shfl_xor(lm, off));
    float s = 0.f;
    uint32_t wbase = (uint32_t)(r * 4096 + (lane & 1) * 8);
#pragma unroll
    for (int kk = 0; kk < 8; ++kk) {
      bf16x4 pb;
      pb[0] = (bf16)__expf(rv[kk].x - lm);
      pb[1] = (bf16)__expf(rv[kk].y - lm);
      pb[2] = (bf16)__expf(rv[kk].z - lm);
      pb[3] = (bf16)__expf(rv[kk].w - lm);
      s += (float)pb[0] + (float)pb[1] + (float)pb[2] + (float)pb[3];
      uint32_t g = (uint32_t)(lane >> 1) + (uint32_t)(kk * 32);
      uint32_t gs = g ^ (uint32_t)(r & 7);  // low-3-bit XOR (granule swizzle)
      *(bf16x4*)(Pc + wbase + gs * 16) = pb;
    }
#pragma unroll
    for (int off = 32; off > 0; off >>= 1) s += __shfl_xor(s, off);
    if (lane == 0) rsum[r] = s;
  }
  __syncthreads();

  // ---- phase 2: out[q0..q0+16)[d0..d0+16) = P @ V^T-frag, MFMA ----
  int dl = (w << 4) + (lane & 15);
  const bf16* vrow = Vtb + (size_t)dl * S + (lane >> 4) * 8;
  uint32_t rl = (uint32_t)(lane & 15);
  uint32_t abase = rl * 4096;
  uint32_t rx = rl & 7;
  f32x4 acc0 = {0.f, 0.f, 0.f, 0.f}, acc1 = {0.f, 0.f, 0.f, 0.f};
#pragma unroll 4
  for (int k0 = 0; k0 < S; k0 += 64) {
    uint32_t g0 = (uint32_t)(k0 >> 3) + (uint32_t)(lane >> 4);
    bf16x8 a0 = *(const bf16x8*)(Pc + abase + ((g0 ^ rx) * 16));
    bf16x8 b0 = *(const bf16x8*)(vrow + k0);
    acc0 = __builtin_amdgcn_mfma_f32_16x16x32_bf16(a0, b0, acc0, 0, 0, 0);
    uint32_t g1 = g0 + 4;
    bf16x8 a1 = *(const bf16x8*)(Pc + abase + ((g1 ^ rx) * 16));
    bf16x8 b1 = *(const bf16x8*)(vrow + k0 + 32);
    acc1 = __builtin_amdgcn_mfma_f32_16x16x32_bf16(a1, b1, acc1, 0, 0, 0);
  }
  f32x4 accs = acc0 + acc1;
#pragma unroll
  for (int reg = 0; reg < 4; ++reg) {
    int m = ((lane >> 4) << 2) + reg;  // C/D layout: row=(lane>>4)*4+reg
    outb[(size_t)(q0 + m) * D + dl] = accs[reg] / rsum[m];
  }
}

// ---------------------------------------------------------------------------
extern "C" void kernel_launch(void* const* d_in, const int* in_sizes, int n_in,
                              void* d_out, int out_size, void* d_ws, size_t ws_size,
                              hipStream_t stream) {
  const float* Q  = (const float*)d_in[0];
  const float* Km = (const float*)d_in[1];
  const float* V  = (const float*)d_in[2];
  const float* W1 = (const float*)d_in[3];
  const float* b1 = (const float*)d_in[4];
  const float* W2 = (const float*)d_in[5];
  const float* b2 = (const float*)d_in[6];
  float* out = (float*)d_out;
  char* ws = (char*)d_ws;

  // layout: W1t 16M | W2t 16M | Qb16 2M | Kb16 2M | X (Sc bf16 / adj f32,
  // aliased) G*16M | h G*16M.  footprint = 36M + G*32M bytes.
  // Vt (bf16 [G][D][S], G*256KB) aliases the h region: written AFTER the
  // W2 gemm consumed h each group iteration, consumed by smav.
  bf16* W1t  = (bf16*)ws;
  bf16* W2t  = (bf16*)(ws + 16777216);
  bf16* Qb16 = (bf16*)(ws + 33554432);
  bf16* Kb16 = (bf16*)(ws + 35651584);

  transpose_cast<<<dim3(H / 64, S / 64), 256, 0, stream>>>(W1, W1t, S, H);
  transpose_cast<<<dim3(S / 64, H / 64), 256, 0, stream>>>(W2, W2t, H, S);
  cast_bf16<<<dim3(NB * S * D / 1024), 256, 0, stream>>>(Q, Qb16);
  cast_bf16<<<dim3(NB * S * D / 1024), 256, 0, stream>>>(Km, Kb16);

  int G = 1;
  if (ws_size >= 306184192ULL) G = 8;        // 292 MiB (R7 ran G=8 OK)
  else if (ws_size >= 171966464ULL) G = 4;
  else if (ws_size >= 104857600ULL) G = 2;

  bf16* Sc   = (bf16*)(ws + 37748736);
  float* adj = (float*)(ws + 37748736);
  bf16* h    = (bf16*)(ws + 37748736 + (size_t)G * 16777216);
  bf16* Vt   = h;  // alias, see layout note

  for (int b0 = 0; b0 < NB; b0 += G) {
    // scores = (Q @ K^T) / 8 via MFMA (K-dim = 64: keep the verified gemm_bt)
    gemm_bt<0, 1><<<dim3(S / 256, S / 128, G), 256, 0, stream>>>(
        Qb16 + (size_t)b0 * S * D, Kb16 + (size_t)b0 * S * D, nullptr, Sc,
        0.125f, S, S, D, (long)S * D, (long)S * D, (long)S * S);
    // big MLP GEMMs on the 4-barrier overlap schedule (16x16x32, verified)
    gemm256<1, 1><<<dim3(H / 256, S / 256, G), 512, 0, stream>>>(
        Sc, W1t, b1, h, 1.0f, S, H, S, (long)S * S, 0L, (long)S * H);
    gemm256<0, 0><<<dim3(S / 256, S / 256, G), 512, 0, stream>>>(
        h, W2t, b2, adj, 1.0f, S, S, H, (long)S * H, 0L, (long)S * S);
    // V^T bf16 into the now-dead h region, then fused softmax + AV on MFMA
    vt_cast<<<dim3(S / 64, G), 256, 0, stream>>>(V + (size_t)b0 * S * D, Vt);
    smav<<<dim3(S / 16, G), 256, 0, stream>>>(
        adj, Vt, out + (size_t)b0 * S * D, (long)S * S);
  }
}

// Round 6
// 644.225 us; speedup vs baseline: 1.1063x; 1.0241x over previous
//
#include <hip/hip_runtime.h>
#include <hip/hip_bf16.h>
#include <stdint.h>

#define S 2048
#define D 64
#define H 4096
#define NB 8

typedef __bf16 bf16;
typedef __attribute__((ext_vector_type(8))) __bf16 bf16x8;
typedef __attribute__((ext_vector_type(4))) __bf16 bf16x4;
typedef __attribute__((ext_vector_type(4))) float f32x4;

// Raw LDS-DMA, invisible to the compiler's waitcnt pass (no auto vmcnt(0)).
// M0 = wave-uniform LDS byte offset; HW adds lane*16B. (R5-verified.)
__device__ __forceinline__ void dma16_raw(const bf16* g, uint32_t m0_bytes) {
  uint32_t m0s = __builtin_amdgcn_readfirstlane(m0_bytes);
  asm volatile("s_mov_b32 m0, %1\n\t"
               "global_load_lds_dwordx4 %0, off"
               :: "v"(g), "s"(m0s) : "memory");
}

__device__ __forceinline__ uint32_t lds_off_bytes(const void* p) {
  return (uint32_t)(uintptr_t)(__attribute__((address_space(3))) const void*)p;
}

// ---------------------------------------------------------------------------
// Transpose + cast: W [K][N] f32  ->  Wt [N][K] bf16   (weights, once per call)
// ---------------------------------------------------------------------------
__global__ __launch_bounds__(256) void transpose_cast(const float* __restrict__ W,
                                                      bf16* __restrict__ Wt,
                                                      int K, int N) {
  __shared__ float tile[64][65];
  int k0 = blockIdx.y * 64, n0 = blockIdx.x * 64;
  int c = threadIdx.x & 63;
  int r4 = threadIdx.x >> 6;
#pragma unroll
  for (int i = 0; i < 16; ++i) {
    int r = i * 4 + r4;
    tile[r][c] = W[(size_t)(k0 + r) * N + n0 + c];
  }
  __syncthreads();
#pragma unroll
  for (int i = 0; i < 16; ++i) {
    int r = i * 4 + r4;
    Wt[(size_t)(n0 + r) * K + k0 + c] = (bf16)tile[c][r];
  }
}

// ---------------------------------------------------------------------------
// Batched transpose + cast for V: V [z][S][D] f32 -> Vt [z][D][S] bf16.
// ---------------------------------------------------------------------------
__global__ __launch_bounds__(256) void vt_cast(const float* __restrict__ V,
                                               bf16* __restrict__ Vt) {
  __shared__ float tile[64][65];
  int z = blockIdx.y;
  int s0 = blockIdx.x * 64;
  const float* Vb = V + (size_t)z * (S * D);
  bf16* Vtb = Vt + (size_t)z * (D * S);
  int c = threadIdx.x & 63;
  int r4 = threadIdx.x >> 6;
#pragma unroll
  for (int i = 0; i < 16; ++i) {
    int r = i * 4 + r4;
    tile[r][c] = Vb[(size_t)(s0 + r) * D + c];
  }
  __syncthreads();
#pragma unroll
  for (int i = 0; i < 16; ++i) {
    int r = i * 4 + r4;  // r = d index
    Vtb[(size_t)r * S + s0 + c] = (bf16)tile[c][r];
  }
}

// ---------------------------------------------------------------------------
// Elementwise cast f32 -> bf16 (for Q, K). One float4 per thread.
// ---------------------------------------------------------------------------
__global__ __launch_bounds__(256) void cast_bf16(const float* __restrict__ x,
                                                 bf16* __restrict__ y) {
  int i = blockIdx.x * 256 + threadIdx.x;
  f32x4 v = ((const f32x4*)x)[i];
  bf16x4 o;
  o[0] = (bf16)v.x; o[1] = (bf16)v.y; o[2] = (bf16)v.z; o[3] = (bf16)v.w;
  ((bf16x4*)y)[i] = o;
}

// ---------------------------------------------------------------------------
// gemm_bt: kept (verified) for QK^T only (K=64 -> no deep pipeline to fill).
// ---------------------------------------------------------------------------
template <int RELU, int OUTBF16>
__global__ __launch_bounds__(256, 2) void gemm_bt(const bf16* __restrict__ A,
                                                  const bf16* __restrict__ Bt,
                                                  const float* __restrict__ bias,
                                                  void* __restrict__ Cv,
                                                  float scale,
                                                  int M, int N, int K,
                                                  long strideA, long strideB,
                                                  long strideC) {
  __shared__ __align__(16) bf16 smem[24576];
  int tid = threadIdx.x;
  int lane = tid & 63;
  int w = tid >> 6;

  int m0 = blockIdx.y * 128, n0 = blockIdx.x * 256;
  const bf16* Ab = A + (size_t)blockIdx.z * strideA;
  const bf16* Btb = Bt + (size_t)blockIdx.z * strideB;

  int grow = tid >> 2;
  int gcol = (((lane & 3) ^ ((lane >> 3) & 3)) * 8);
  const bf16* gA0 = Ab + (size_t)(m0 + grow) * K + gcol;
  const bf16* gA1 = gA0 + (size_t)64 * K;
  const bf16* gB0 = Btb + (size_t)(n0 + grow) * K + gcol;
  const bf16* gB1 = gB0 + (size_t)64 * K;
  const bf16* gB2 = gB0 + (size_t)128 * K;
  const bf16* gB3 = gB0 + (size_t)192 * K;

  uint32_t ldsBase = lds_off_bytes(&smem[0]);
  uint32_t wb = (uint32_t)(w * 1024);
  uint32_t mA[2], mB[2];
  mA[0] = ldsBase + wb;          mA[1] = ldsBase + 8192 + wb;
  mB[0] = ldsBase + 16384 + wb;  mB[1] = ldsBase + 32768 + wb;

  int mw = (w & 1) * 64, nw = (w >> 1) * 128;
  int lr = lane & 15;
  int ck = lane >> 4;
  int swz = (ck ^ ((lr >> 1) & 3)) * 8;
  const bf16* paBase = smem + (size_t)(mw + lr) * 32 + swz;
  const bf16* pbBase = smem + 8192 + (size_t)(nw + lr) * 32 + swz;

  f32x4 zero = {0.f, 0.f, 0.f, 0.f};
  f32x4 acc[4][8];
#pragma unroll
  for (int mt = 0; mt < 4; ++mt)
#pragma unroll
    for (int nt = 0; nt < 8; ++nt) acc[mt][nt] = zero;

  const int niter = K / 32;

#define STAGE(buf, koff)                                 \
  do {                                                   \
    dma16_raw(gA0 + (koff), mA[buf]);                    \
    dma16_raw(gA1 + (koff), mA[buf] + 4096);             \
    dma16_raw(gB0 + (koff), mB[buf]);                    \
    dma16_raw(gB1 + (koff), mB[buf] + 4096);             \
    dma16_raw(gB2 + (koff), mB[buf] + 8192);             \
    dma16_raw(gB3 + (koff), mB[buf] + 12288);            \
  } while (0)

  STAGE(0, 0);
  STAGE(1, 32);

  for (int it = 0; it < niter; ++it) {
    int buf = it & 1;
    asm volatile("s_waitcnt vmcnt(6)\n\ts_barrier" ::: "memory");
    const bf16* pa = paBase + buf * 4096;
    const bf16* pb = pbBase + buf * 8192;
    bf16x8 af[4], bfr[8];
#pragma unroll
    for (int mt = 0; mt < 4; ++mt) af[mt] = *(const bf16x8*)(pa + mt * (16 * 32));
#pragma unroll
    for (int nt = 0; nt < 8; ++nt) bfr[nt] = *(const bf16x8*)(pb + nt * (16 * 32));
    asm volatile("s_waitcnt lgkmcnt(0)\n\ts_barrier" ::: "memory");
    int kpre = it + 2 < niter ? (it + 2) * 32 : (niter - 1) * 32;
    STAGE(buf, kpre);
#pragma unroll
    for (int mt = 0; mt < 4; ++mt)
#pragma unroll
      for (int nt = 0; nt < 8; ++nt)
        acc[mt][nt] = __builtin_amdgcn_mfma_f32_16x16x32_bf16(af[mt], bfr[nt],
                                                              acc[mt][nt], 0, 0, 0);
  }
#undef STAGE
  asm volatile("s_waitcnt vmcnt(0)" ::: "memory");

  int mbase = m0 + mw + (lane >> 4) * 4;
  int nbase = n0 + nw + (lane & 15);
#pragma unroll
  for (int mt = 0; mt < 4; ++mt) {
#pragma unroll
    for (int nt = 0; nt < 8; ++nt) {
      int n = nbase + nt * 16;
      float bv = bias ? bias[n] : 0.f;
#pragma unroll
      for (int reg = 0; reg < 4; ++reg) {
        int m = mbase + mt * 16 + reg;
        float v = acc[mt][nt][reg] * scale + bv;
        if (RELU) v = fmaxf(v, 0.f);
        if (OUTBF16) {
          bf16* C = (bf16*)Cv + (size_t)blockIdx.z * strideC;
          C[(size_t)m * N + n] = (bf16)v;
        } else {
          float* C = (float*)Cv + (size_t)blockIdx.z * strideC;
          C[(size_t)m * N + n] = v;
        }
      }
    }
  }
}

// ---------------------------------------------------------------------------
// gemm256: 256x256 tile, BK=64, 512 threads (8 waves as 2Mx4N, 128x64/wave),
// 128 KiB LDS, counted-vmcnt quadrant schedule.
// R13: rotated pipeline — the old section 1 (reads+stage, ZERO MFMA) idled
// the matrix pipe every K-tile (sections were 0/16/16/32 MFMA; measured
// MfmaUtil 50%). MFMA_Q(1,0) now carries across the tile boundary into the
// next tile's section 1 -> sections 16/16/16/16; every inter-barrier window
// feeds the matrix pipe; S4 stages before its MFMA cluster so the VMC4
// residual drains under compute.
// Invariants (re-derived for the rotation):
//  - DMA global issue order and once-per-tile vmcnt(4) are IDENTICAL to the
//    R10-verified order (trailing STAGE_AH is the same slot/offset as old
//    S1's) -> at each VMC4 exactly the two tile+2 half-stages (4 loads) are
//    outstanding; everything section 1 reads (A-h0 staged 2 tiles ago,
//    B-h0 staged this tile's S2) is strictly older -> drained on all waves
//    before the rendezvous barrier.
//  - register WARs (carried MFMA reading old af/bf0 before the overwriting
//    RDA/RDB in the same section) are compiler-ordered issue deps.
//  - LDS WARs unchanged: overwrites sit >=1 barrier after last read's lgkmcnt.
// Per-acc MFMA order unchanged -> bit-identical numerics.
// 16x16x32 read layout is the PMC-verified conflict-free one (R12 note):
// do not change the fragment read pattern without re-measuring
// SQ_LDS_BANK_CONFLICT.
// ---------------------------------------------------------------------------
template <int RELU, int OUTBF16>
__global__ __launch_bounds__(512, 2) void gemm256(const bf16* __restrict__ A,
                                                  const bf16* __restrict__ Bt,
                                                  const float* __restrict__ bias,
                                                  void* __restrict__ Cv,
                                                  float scale,
                                                  int M, int N, int K,
                                                  long strideA, long strideB,
                                                  long strideC) {
  __shared__ __align__(16) bf16 smem[65536];  // 128 KiB
  const char* smc = (const char*)&smem[0];

  int tid = threadIdx.x;
  int lane = tid & 63;
  int w = tid >> 6;
  int wm = w >> 2, wn = w & 3;  // 2M x 4N wave grid

  // bijective XCD swizzle (m204) over the x-y plane; z = batch untouched.
  unsigned gx = gridDim.x;
  unsigned nwg = gx * gridDim.y;
  unsigned flat = blockIdx.y * gx + blockIdx.x;
  unsigned q = nwg >> 3, r = nwg & 7, xcd = flat & 7, idx = flat >> 3;
  unsigned wg = (xcd < r ? xcd * (q + 1) : r * (q + 1) + (xcd - r) * q) + idx;
  int n0 = (int)(wg % gx) * 256;
  int m0 = (int)(wg / gx) * 256;

  const bf16* Ab = A + (size_t)blockIdx.z * strideA;
  const bf16* Btb = Bt + (size_t)blockIdx.z * strideB;

  // Staging: thread t covers LDS byte 16*t of each 8 KiB (64-row) load chunk:
  // row = t>>3, granule = t&7. Pre-swizzled global granule = (t&7)^(row&7).
  int trow = tid >> 3;
  int tg = (tid & 7) ^ (trow & 7);
  const bf16* pgA = Ab + (size_t)(m0 + trow) * K + tg * 8;
  const bf16* pgB = Btb + (size_t)(n0 + trow) * K + tg * 8;
  const size_t s64K = (size_t)K * 64;

  uint32_t ldsBase = lds_off_bytes(&smem[0]);
  uint32_t mb = ldsBase + (uint32_t)(w * 1024);  // wave-uniform DMA base

  // LDS read bases. A-frag (16x16x32): row=lane&15, k=(lane>>4)*8.
  int j = lane >> 4, b2 = (lane >> 2) & 1;
  uint32_t rbA0 = (uint32_t)(wm * 8192 + (lane & 15) * 128 +
                             ((j ^ (lane & 3)) * 16) + b2 * 64);
  uint32_t rbA1 = rbA0 ^ 64u;
  uint32_t rbB0 = (uint32_t)(65536 + wn * 4096 + (lane & 15) * 128 +
                             ((j ^ (lane & 3)) * 16) + b2 * 64);
  uint32_t rbB1 = rbB0 ^ 64u;

  f32x4 acc[8][4];  // [qa*4+mt][qb*2+nt]
#pragma unroll
  for (int a = 0; a < 8; ++a)
#pragma unroll
    for (int b = 0; b < 2 * 2; ++b) acc[a][b] = (f32x4){0.f, 0.f, 0.f, 0.f};

  bf16x8 af[4][2];   // current A quad [mt][kk]
  bf16x8 bf0[2][2];  // B quad 0 (held across the tile, no re-read)
  bf16x8 bf1[2][2];  // B quad 1

#define STG_A(PI, HH, LL, KC) \
  dma16_raw(pgA + (size_t)(2 * (HH) + (LL)) * s64K + (KC), \
            mb + (PI) * 32768 + (HH) * 16384 + (LL) * 8192)
#define STG_B(PI, HH, LL, KC) \
  dma16_raw(pgB + (size_t)(2 * (HH) + (LL)) * s64K + (KC), \
            mb + 65536 + (PI) * 32768 + (HH) * 16384 + (LL) * 8192)
#define STAGE_AH(PI, HH, KC) do { STG_A(PI, HH, 0, KC); STG_A(PI, HH, 1, KC); } while (0)
#define STAGE_BH(PI, HH, KC) do { STG_B(PI, HH, 0, KC); STG_B(PI, HH, 1, KC); } while (0)

#define RDA(PI, QA)                                                            \
  do {                                                                        \
    _Pragma("unroll") for (int mt = 0; mt < 4; ++mt) {                        \
      af[mt][0] = *(const bf16x8*)(smc + rbA0 + ((PI) * 32768 + (QA) * 16384 + mt * 2048)); \
      af[mt][1] = *(const bf16x8*)(smc + rbA1 + ((PI) * 32768 + (QA) * 16384 + mt * 2048)); \
    }                                                                         \
  } while (0)
#define RDB(PI, QB, BF)                                                        \
  do {                                                                        \
    _Pragma("unroll") for (int nt = 0; nt < 2; ++nt) {                        \
      BF[nt][0] = *(const bf16x8*)(smc + rbB0 + ((PI) * 32768 + (QB) * 16384 + nt * 2048)); \
      BF[nt][1] = *(const bf16x8*)(smc + rbB1 + ((PI) * 32768 + (QB) * 16384 + nt * 2048)); \
    }                                                                         \
  } while (0)

#define MFMA_Q(QA, QB, BF)                                                     \
  do {                                                                        \
    __builtin_amdgcn_s_setprio(1);                                            \
    _Pragma("unroll") for (int mt = 0; mt < 4; ++mt)                          \
      _Pragma("unroll") for (int nt = 0; nt < 2; ++nt) {                      \
        f32x4 c = acc[(QA) * 4 + mt][(QB) * 2 + nt];                          \
        c = __builtin_amdgcn_mfma_f32_16x16x32_bf16(af[mt][0], BF[nt][0], c, 0, 0, 0); \
        c = __builtin_amdgcn_mfma_f32_16x16x32_bf16(af[mt][1], BF[nt][1], c, 0, 0, 0); \
        acc[(QA) * 4 + mt][(QB) * 2 + nt] = c;                                \
      }                                                                       \
    __builtin_amdgcn_s_setprio(0);                                            \
  } while (0)

#define BAR() asm volatile("s_barrier" ::: "memory")
#define VMC4() asm volatile("s_waitcnt vmcnt(4)" ::: "memory")

  // Rotated K-tile: S2/S3/S4 + trailing S1 of the NEXT tile (carries this
  // tile's last MFMA quadrant). c1 = k-offset of tile+1, c2 = tile+2
  // (tail-clamped: data only; dest slots never read).
#define TILE2(PI, TT)                                              \
  do {                                                             \
    int c1 = ((TT) + 1 < NT ? (TT) + 1 : NT - 1) * 64;             \
    int c2 = ((TT) + 2 < NT ? (TT) + 2 : NT - 1) * 64;             \
    /* S2 */                                                       \
    MFMA_Q(0, 0, bf0);                                             \
    RDB(PI, 1, bf1);                                               \
    STAGE_BH((PI) ^ 1, 0, c1);                                     \
    BAR();                                                         \
    /* S3 */                                                       \
    MFMA_Q(0, 1, bf1);                                             \
    RDA(PI, 1);                                                    \
    STAGE_AH(PI, 0, c2);                                           \
    BAR();                                                         \
    /* S4: stage first so VMC4 residual drains under the MFMAs */  \
    STAGE_BH(PI, 1, c2);                                           \
    MFMA_Q(1, 1, bf1);                                             \
    VMC4();                                                        \
    BAR();                                                         \
    /* trailing S1 of tile TT+1 (carried MFMA of tile TT) */       \
    MFMA_Q(1, 0, bf0);                                             \
    if ((TT) + 1 < NT) {                                           \
      RDA((PI) ^ 1, 0);                                            \
      RDB((PI) ^ 1, 0, bf0);                                       \
      STAGE_AH(PI, 1, c2);                                         \
      BAR();                                                       \
    }                                                              \
  } while (0)

  // Prologue: issue halves in steady-state order; vmcnt(4) (= 4 loads =
  // the two tile-1 ph3/ph4-slot halves) leaves exactly AH(1,0),BH(1,1)
  // outstanding; all tile-0 halves drained.
  STAGE_AH(0, 0, 0);
  STAGE_BH(0, 1, 0);
  STAGE_AH(0, 1, 0);
  STAGE_BH(0, 0, 0);
  STAGE_AH(1, 0, 64);
  STAGE_BH(1, 1, 64);
  asm volatile("s_waitcnt vmcnt(4)\n\ts_barrier" ::: "memory");

  const int NT = K / 64;  // even (K = 2048 or 4096)

  // Peeled S1 of tile 0 (no carried MFMA yet).
  RDA(0, 0);
  RDB(0, 0, bf0);
  STAGE_AH(1, 1, 64);
  BAR();

  for (int T = 0; T < NT; T += 2) {
    TILE2(0, T);
    TILE2(1, T + 1);
  }
#undef TILE2
#undef VMC4
#undef BAR
#undef MFMA_Q
#undef RDB
#undef RDA
#undef STAGE_BH
#undef STAGE_AH
#undef STG_B
#undef STG_A

  asm volatile("s_waitcnt vmcnt(0)" ::: "memory");

  int rowb = m0 + wm * 64 + ((lane >> 4) << 2);
  int colb = n0 + wn * 32 + (lane & 15);
#pragma unroll
  for (int fn = 0; fn < 4; ++fn) {
    int n = colb + (fn >> 1) * 128 + (fn & 1) * 16;
    float bv = bias ? bias[n] : 0.f;
#pragma unroll
    for (int fm = 0; fm < 8; ++fm) {
      int mrow = rowb + (fm >> 2) * 128 + (fm & 3) * 16;
#pragma unroll
      for (int reg = 0; reg < 4; ++reg) {
        float v = acc[fm][fn][reg] * scale + bv;
        if (RELU) v = fmaxf(v, 0.f);
        int m = mrow + reg;
        if (OUTBF16) {
          bf16* C = (bf16*)Cv + (size_t)blockIdx.z * strideC;
          C[(size_t)m * N + n] = (bf16)v;
        } else {
          float* C = (float*)Cv + (size_t)blockIdx.z * strideC;
          C[(size_t)m * N + n] = v;
        }
      }
    }
  }
}

// ---------------------------------------------------------------------------
// smav: fused softmax + attn@V on MFMA (R9; replaced 128us scalar AV).
// ---------------------------------------------------------------------------
__global__ __launch_bounds__(256) void smav(const float* __restrict__ adj,
                                            const bf16* __restrict__ Vt,
                                            float* __restrict__ out,
                                            long adjStride) {
  int z = blockIdx.y;
  const float* adjb = adj + (size_t)z * adjStride;
  const bf16* Vtb = Vt + (size_t)z * (D * S);
  float* outb = out + (size_t)z * (S * D);
  int q0 = blockIdx.x * 16;
  __shared__ __align__(16) bf16 P[16 * 2048];  // 64 KiB, swizzled
  __shared__ float rsum[16];
  int tid = threadIdx.x, w = tid >> 6, lane = tid & 63;
  char* Pc = (char*)&P[0];

  // ---- phase 1: softmax (rows w*4 .. w*4+3) ----
#pragma unroll
  for (int i = 0; i < 4; ++i) {
    int r = w * 4 + i;
    const float* rowp = adjb + (size_t)(q0 + r) * S + lane * 4;
    f32x4 rv[8];
    float lm = -1e30f;
#pragma unroll
    for (int kk = 0; kk < 8; ++kk) {
      rv[kk] = *(const f32x4*)(rowp + kk * 256);
      lm = fmaxf(lm, fmaxf(fmaxf(rv[kk].x, rv[kk].y), fmaxf(rv[kk].z, rv[kk].w)));
    }
#pragma unroll
    for (int off = 32; off > 0; off >>= 1) lm = fmaxf(lm, __shfl_xor(lm, off));
    float s = 0.f;
    uint32_t wbase = (uint32_t)(r * 4096 + (lane & 1) * 8);
#pragma unroll
    for (int kk = 0; kk < 8; ++kk) {
      bf16x4 pb;
      pb[0] = (bf16)__expf(rv[kk].x - lm);
      pb[1] = (bf16)__expf(rv[kk].y - lm);
      pb[2] = (bf16)__expf(rv[kk].z - lm);
      pb[3] = (bf16)__expf(rv[kk].w - lm);
      s += (float)pb[0] + (float)pb[1] + (float)pb[2] + (float)pb[3];
      uint32_t g = (uint32_t)(lane >> 1) + (uint32_t)(kk * 32);
      uint32_t gs = g ^ (uint32_t)(r & 7);  // low-3-bit XOR (granule swizzle)
      *(bf16x4*)(Pc + wbase + gs * 16) = pb;
    }
#pragma unroll
    for (int off = 32; off > 0; off >>= 1) s += __shfl_xor(s, off);
    if (lane == 0) rsum[r] = s;
  }
  __syncthreads();

  // ---- phase 2: out[q0..q0+16)[d0..d0+16) = P @ V^T-frag, MFMA ----
  int dl = (w << 4) + (lane & 15);
  const bf16* vrow = Vtb + (size_t)dl * S + (lane >> 4) * 8;
  uint32_t rl = (uint32_t)(lane & 15);
  uint32_t abase = rl * 4096;
  uint32_t rx = rl & 7;
  f32x4 acc0 = {0.f, 0.f, 0.f, 0.f}, acc1 = {0.f, 0.f, 0.f, 0.f};
#pragma unroll 4
  for (int k0 = 0; k0 < S; k0 += 64) {
    uint32_t g0 = (uint32_t)(k0 >> 3) + (uint32_t)(lane >> 4);
    bf16x8 a0 = *(const bf16x8*)(Pc + abase + ((g0 ^ rx) * 16));
    bf16x8 b0 = *(const bf16x8*)(vrow + k0);
    acc0 = __builtin_amdgcn_mfma_f32_16x16x32_bf16(a0, b0, acc0, 0, 0, 0);
    uint32_t g1 = g0 + 4;
    bf16x8 a1 = *(const bf16x8*)(Pc + abase + ((g1 ^ rx) * 16));
    bf16x8 b1 = *(const bf16x8*)(vrow + k0 + 32);
    acc1 = __builtin_amdgcn_mfma_f32_16x16x32_bf16(a1, b1, acc1, 0, 0, 0);
  }
  f32x4 accs = acc0 + acc1;
#pragma unroll
  for (int reg = 0; reg < 4; ++reg) {
    int m = ((lane >> 4) << 2) + reg;  // C/D layout: row=(lane>>4)*4+reg
    outb[(size_t)(q0 + m) * D + dl] = accs[reg] / rsum[m];
  }
}

// ---------------------------------------------------------------------------
extern "C" void kernel_launch(void* const* d_in, const int* in_sizes, int n_in,
                              void* d_out, int out_size, void* d_ws, size_t ws_size,
                              hipStream_t stream) {
  const float* Q  = (const float*)d_in[0];
  const float* Km = (const float*)d_in[1];
  const float* V  = (const float*)d_in[2];
  const float* W1 = (const float*)d_in[3];
  const float* b1 = (const float*)d_in[4];
  const float* W2 = (const float*)d_in[5];
  const float* b2 = (const float*)d_in[6];
  float* out = (float*)d_out;
  char* ws = (char*)d_ws;

  // layout: W1t 16M | W2t 16M | Qb16 2M | Kb16 2M | X (Sc bf16 / adj f32,
  // aliased) G*16M | h G*16M.  footprint = 36M + G*32M bytes.
  // Vt (bf16 [G][D][S], G*256KB) aliases the h region: written AFTER the
  // W2 gemm consumed h each group iteration, consumed by smav.
  bf16* W1t  = (bf16*)ws;
  bf16* W2t  = (bf16*)(ws + 16777216);
  bf16* Qb16 = (bf16*)(ws + 33554432);
  bf16* Kb16 = (bf16*)(ws + 35651584);

  transpose_cast<<<dim3(H / 64, S / 64), 256, 0, stream>>>(W1, W1t, S, H);
  transpose_cast<<<dim3(S / 64, H / 64), 256, 0, stream>>>(W2, W2t, H, S);
  cast_bf16<<<dim3(NB * S * D / 1024), 256, 0, stream>>>(Q, Qb16);
  cast_bf16<<<dim3(NB * S * D / 1024), 256, 0, stream>>>(Km, Kb16);

  int G = 1;
  if (ws_size >= 306184192ULL) G = 8;        // 292 MiB (R7 ran G=8 OK)
  else if (ws_size >= 171966464ULL) G = 4;
  else if (ws_size >= 104857600ULL) G = 2;

  bf16* Sc   = (bf16*)(ws + 37748736);
  float* adj = (float*)(ws + 37748736);
  bf16* h    = (bf16*)(ws + 37748736 + (size_t)G * 16777216);
  bf16* Vt   = h;  // alias, see layout note

  for (int b0 = 0; b0 < NB; b0 += G) {
    // scores = (Q @ K^T) / 8 via MFMA (K-dim = 64: keep the verified gemm_bt)
    gemm_bt<0, 1><<<dim3(S / 256, S / 128, G), 256, 0, stream>>>(
        Qb16 + (size_t)b0 * S * D, Kb16 + (size_t)b0 * S * D, nullptr, Sc,
        0.125f, S, S, D, (long)S * D, (long)S * D, (long)S * S);
    // big MLP GEMMs on the rotated 4-barrier schedule (16x16x32, verified)
    gemm256<1, 1><<<dim3(H / 256, S / 256, G), 512, 0, stream>>>(
        Sc, W1t, b1, h, 1.0f, S, H, S, (long)S * S, 0L, (long)S * H);
    gemm256<0, 0><<<dim3(S / 256, S / 256, G), 512, 0, stream>>>(
        h, W2t, b2, adj, 1.0f, S, S, H, (long)S * H, 0L, (long)S * S);
    // V^T bf16 into the now-dead h region, then fused softmax + AV on MFMA
    vt_cast<<<dim3(S / 64, G), 256, 0, stream>>>(V + (size_t)b0 * S * D, Vt);
    smav<<<dim3(S / 16, G), 256, 0, stream>>>(
        adj, Vt, out + (size_t)b0 * S * D, (long)S * S);
  }
}